// Round 7
// baseline (452.557 us; speedup 1.0000x reference)
//
#include <hip/hip_runtime.h>
#include <math.h>

namespace {

constexpr int kB   = 64;
constexpr int kCin = 8;
constexpr int kR   = 800;
constexpr int kNC  = 128;
constexpr int kO   = 16;
constexpr int CT   = 256;   // conversion kernel TPB
constexpr int MT   = 256;   // main kernel TPB (R7: 256, 3-4 rows/thread)
constexpr int FT   = 512;   // fallback kernel TPB (proven R6 structure)
constexpr int NITER = 3;
constexpr size_t WS_NEEDED =
    (size_t)kNC * kO * kR * kCin * sizeof(unsigned short);  // 26,214,400 B

typedef _Float16 half2v __attribute__((ext_vector_type(2)));

__device__ __forceinline__ half2v u2h(unsigned int u) {
  union { unsigned int u; half2v h; } x;
  x.u = u;
  return x.h;
}

__device__ __forceinline__ unsigned short f2h(float f) {
  union { _Float16 h; unsigned short s; } x;
  x.h = (_Float16)f;
  return x.s;
}

// DPP adds: xor1 = quad_perm{1,0,3,2}=0xB1, xor2 = quad_perm{2,3,0,1}=0x4E,
// mir8 = row_half_mirror (0x141): lane i <-> 7-i within each 8-lane half-row.
__device__ __forceinline__ float dpp_xor1_add(float v) {
  const int o = __builtin_amdgcn_mov_dpp(__float_as_int(v), 0xB1, 0xF, 0xF, true);
  return v + __int_as_float(o);
}
__device__ __forceinline__ float dpp_xor2_add(float v) {
  const int o = __builtin_amdgcn_mov_dpp(__float_as_int(v), 0x4E, 0xF, 0xF, true);
  return v + __int_as_float(o);
}
__device__ __forceinline__ float dpp_mir8_add(float v) {
  const int o = __builtin_amdgcn_mov_dpp(__float_as_int(v), 0x141, 0xF, 0xF, true);
  return v + __int_as_float(o);
}

// ---- W conversion: fp32 [c][r][i][o] -> fp16 [c][o][r][i] (uint4 = 8 i's) --
// R1-proven streaming 32-row tiles: 16.9 KB LDS -> 8 blocks/CU, 3200 blocks.
__global__ __launch_bounds__(CT) void conv_w(const float* __restrict__ W,
                                             unsigned short* __restrict__ Wb) {
  __shared__ float tile[32 * 132];   // 32 r-rows x 128 cols (+4 pad)
  const int blk = blockIdx.x;        // c*25 + rt
  const int c  = blk / 25;
  const int rt = blk - c * 25;
  const int r0 = rt * 32;
  const int t  = threadIdx.x;

  const float4* src =
      reinterpret_cast<const float4*>(W + ((size_t)c * kR + r0) * kCin * kO);
  #pragma unroll
  for (int k2 = 0; k2 < 4; ++k2) {
    const int i4  = t + k2 * CT;
    const float4 v = src[i4];
    const int fi = i4 * 4, row = fi >> 7, pos = fi & 127;
    *reinterpret_cast<float4*>(&tile[row * 132 + pos]) = v;
  }
  __syncthreads();

  const int o = t >> 4;
  #pragma unroll
  for (int k2 = 0; k2 < 2; ++k2) {
    const int rl = (t & 15) + 16 * k2;
    unsigned int pk[4];
    #pragma unroll
    for (int q = 0; q < 4; ++q) {
      const unsigned int lo = f2h(tile[rl * 132 + (2 * q + 0) * 16 + o]);
      const unsigned int hi = f2h(tile[rl * 132 + (2 * q + 1) * 16 + o]);
      pk[q] = lo | (hi << 16);
    }
    reinterpret_cast<uint4*>(Wb)[(size_t)(c * kO + o) * kR + (r0 + rl)] =
        make_uint4(pk[0], pk[1], pk[2], pk[3]);
  }
}

// ---- main (R7): 256 threads/block, 3-4 rows/thread, fp32 priors in regs.
// Register model (validated on R0/R2/R3 evidence): per-EU VGPR file = 512;
// __launch_bounds__ 2nd arg = min blocks/CU. (256,4) -> 16 waves/CU -> cap
// 128 VGPR. This removes ALL fp16 pack/unpack of priors (96 cvt + 32 pack
// per thread in R6) and halves per-wave phase-2 reduction overhead (4 waves
// vs 8 per block). Peak reg demand ~112 (u0..u3=64 + w[8]=32 + xp/addr).
__global__ __launch_bounds__(MT, 4) void caps_route(
    const float* __restrict__ x, const unsigned short* __restrict__ Wb,
    float* __restrict__ out) {
  constexpr int RST = 20;               // 17 cols + 3 pad
  __shared__ float red[64 * RST];       // 5.1 KB (64 quad-groups)
  __shared__ float shs[RST];

  const int t = threadIdx.x;
  // XCD swizzle: 16 c's per XCD -> fp16 W working set 3.3 MB < 4 MB L2.
  const int j   = blockIdx.x;
  const int xcd = j & 7;
  const int kk  = j >> 3;               // 0..1023
  const int c   = ((kk >> 6) << 3) + xcd;
  const int b   = kk & 63;

  const float* xb  = x + (size_t)b * kCin * kR;
  const bool  has4 = (t < kR - 3 * MT);   // t < 32 owns a 4th row
  const int   r0 = t, r1 = MT + t, r2 = 2 * MT + t, r3 = 3 * MT + t;

  const uint4* Wc = reinterpret_cast<const uint4*>(Wb) + (size_t)c * kO * kR;

  float u0[kO], u1[kO], u2[kO], u3[kO];
  #pragma unroll
  for (int o = 0; o < kO; ++o) u3[o] = 0.f;

  // Per-row dot: 8-deep uint4 load chunks + fdot2 (R0-proven pattern).
  auto row_dot = [&](int r, float (&uo)[kO]) {
    half2v xp[4];
    #pragma unroll
    for (int q = 0; q < 4; ++q)
      xp[q] = half2v{(_Float16)xb[(2*q) * kR + r], (_Float16)xb[(2*q+1) * kR + r]};
    #pragma unroll
    for (int ob = 0; ob < 2; ++ob) {
      uint4 w[8];
      #pragma unroll
      for (int u = 0; u < 8; ++u) w[u] = Wc[(size_t)(ob * 8 + u) * kR + r];
      #pragma unroll
      for (int u = 0; u < 8; ++u) {
        float a = __builtin_amdgcn_fdot2(u2h(w[u].x), xp[0], 0.f, false);
        a = __builtin_amdgcn_fdot2(u2h(w[u].y), xp[1], a, false);
        a = __builtin_amdgcn_fdot2(u2h(w[u].z), xp[2], a, false);
        a = __builtin_amdgcn_fdot2(u2h(w[u].w), xp[3], a, false);
        uo[ob * 8 + u] = a;
      }
    }
  };

  row_dot(r0, u0);
  row_dot(r1, u1);
  row_dot(r2, u2);
  if (has4) row_dot(r3, u3);

  // -------- Phase 2: 3 routing iterations (all fp32, no pack/unpack) -------
  float l0 = 0.f, l1 = 0.f, l2 = 0.f, l3 = 0.f;
  #pragma unroll
  for (int it = 0; it < NITER; ++it) {
    const float e0 = (it == 0) ? 1.f : __expf(l0);
    const float e1 = (it == 0) ? 1.f : __expf(l1);
    const float e2 = (it == 0) ? 1.f : __expf(l2);

    float sp[kO + 1];
    sp[kO] = e0 + e1 + e2;
    #pragma unroll
    for (int o = 0; o < kO; ++o)
      sp[o] = e0 * u0[o] + e1 * u1[o] + e2 * u2[o];

    if (t < 64) {   // wave-0-uniform: only wave 0 has 4th-row owners
      const float e3 = has4 ? ((it == 0) ? 1.f : __expf(l3)) : 0.f;
      #pragma unroll
      for (int o = 0; o < kO; ++o) sp[o] += e3 * u3[o];
      sp[kO] += e3;
    }

    #pragma unroll
    for (int v = 0; v <= kO; ++v) {
      sp[v] = dpp_xor1_add(sp[v]);
      sp[v] = dpp_xor2_add(sp[v]);
    }
    if ((t & 3) == 0) {
      float* row = &red[(t >> 2) * RST];
      #pragma unroll
      for (int q = 0; q < 4; ++q)
        *reinterpret_cast<float4*>(row + 4 * q) =
            make_float4(sp[4*q], sp[4*q+1], sp[4*q+2], sp[4*q+3]);
      row[16] = sp[16];
    }
    __syncthreads();

    // Merged reduce (R6-proven, zero conflicts): 64 quad-group rows,
    // t = col*8+q; 8-lane DPP group sums the 8 q-partials per col.
    if (t < 136) {
      const int q = t & 7, col = t >> 3;
      float a = 0.f;
      #pragma unroll
      for (int rr = 0; rr < 8; ++rr) a += red[(rr * 8 + q) * RST + col];
      a = dpp_xor1_add(a);
      a = dpp_xor2_add(a);
      a = dpp_mir8_add(a);
      if (q == 0) shs[col] = a;
    }
    __syncthreads();

    float sh[kO];
    #pragma unroll
    for (int o = 0; o < kO; ++o) sh[o] = shs[o];
    const float Zi = 1.f / shs[kO];
    float ss = 0.f;
    #pragma unroll
    for (int o = 0; o < kO; ++o) ss += sh[o] * sh[o];
    const float sn = ss * Zi * Zi;
    const float g  = Zi * sqrtf(sn) / (1.f + sn);

    if (it < NITER - 1) {
      float d0 = 0.f, d1 = 0.f, d2 = 0.f;
      #pragma unroll
      for (int o = 0; o < kO; ++o) {
        d0 += u0[o] * sh[o];
        d1 += u1[o] * sh[o];
        d2 += u2[o] * sh[o];
      }
      l0 += d0 * g;
      l1 += d1 * g;
      l2 += d2 * g;
      if (t < 64) {
        float d3 = 0.f;
        #pragma unroll
        for (int o = 0; o < kO; ++o) d3 += u3[o] * sh[o];
        if (has4) l3 += d3 * g;
      }
    } else {
      // Read shs[t] from LDS (runtime index into regs would go to scratch).
      if (t < kO) out[(size_t)b * kO * kNC + t * kNC + c] = shs[t] * g;
    }
  }
}

// ---- fallback (no workspace): fp32 W direct — R6-proven 512-thread kernel --
__global__ __launch_bounds__(FT, 4) void caps_route_f32(
    const float* __restrict__ x, const float* __restrict__ W,
    float* __restrict__ out) {
  constexpr int RST = 20;
  __shared__ float red[128 * RST];
  __shared__ float shs[RST];

  const int t   = threadIdx.x;
  const int j   = blockIdx.x;
  const int xcd = j & 7;
  const int kk  = j >> 3;
  const int c   = ((kk >> 6) << 3) + xcd;
  const int b   = kk & 63;

  const float* xb  = x + (size_t)b * kCin * kR;
  const bool  has2 = (t < kR - FT);
  const int   r1   = t, r2 = FT + t;

  float P1[kO], P2[kO];
  #pragma unroll
  for (int o = 0; o < kO; ++o) P2[o] = 0.f;
  {
    float xa[kCin];
    #pragma unroll
    for (int i = 0; i < kCin; ++i) xa[i] = xb[i * kR + r1];
    const float* Wc = W + ((size_t)c * kR + r1) * kCin * kO;
    #pragma unroll
    for (int o = 0; o < kO; ++o) {
      float acc = 0.f;
      #pragma unroll
      for (int i = 0; i < kCin; ++i) acc += xa[i] * Wc[i * kO + o];
      P1[o] = acc;
    }
  }
  if (has2) {
    float xa[kCin];
    #pragma unroll
    for (int i = 0; i < kCin; ++i) xa[i] = xb[i * kR + r2];
    const float* Wc = W + ((size_t)c * kR + r2) * kCin * kO;
    #pragma unroll
    for (int o = 0; o < kO; ++o) {
      float acc = 0.f;
      #pragma unroll
      for (int i = 0; i < kCin; ++i) acc += xa[i] * Wc[i * kO + o];
      P2[o] = acc;
    }
  }

  float l1 = 0.f, l2 = 0.f;
  #pragma unroll
  for (int it = 0; it < NITER; ++it) {
    const float e1 = (it == 0) ? 1.f : __expf(l1);
    const float e2 = has2 ? ((it == 0) ? 1.f : __expf(l2)) : 0.f;
    float sp[kO + 1];
    sp[kO] = e1 + e2;
    #pragma unroll
    for (int o = 0; o < kO; ++o) sp[o] = e1 * P1[o] + e2 * P2[o];
    #pragma unroll
    for (int v = 0; v <= kO; ++v) {
      sp[v] = dpp_xor1_add(sp[v]);
      sp[v] = dpp_xor2_add(sp[v]);
    }
    if ((t & 3) == 0) {
      float* row = &red[(t >> 2) * RST];
      #pragma unroll
      for (int q = 0; q < 4; ++q)
        *reinterpret_cast<float4*>(row + 4 * q) =
            make_float4(sp[4*q], sp[4*q+1], sp[4*q+2], sp[4*q+3]);
      row[16] = sp[16];
    }
    __syncthreads();
    if (t < 136) {
      const int q = t & 7, col = t >> 3;
      float a = 0.f;
      #pragma unroll
      for (int rr = 0; rr < 16; ++rr) a += red[(rr * 8 + q) * RST + col];
      a = dpp_xor1_add(a);
      a = dpp_xor2_add(a);
      a = dpp_mir8_add(a);
      if (q == 0) shs[col] = a;
    }
    __syncthreads();
    const float Zi = 1.f / shs[kO];
    float ss = 0.f;
    #pragma unroll
    for (int o = 0; o < kO; ++o) ss += shs[o] * shs[o];
    const float sn = ss * Zi * Zi;
    const float g  = Zi * sqrtf(sn) / (1.f + sn);
    if (it < NITER - 1) {
      float d1 = 0.f, d2 = 0.f;
      #pragma unroll
      for (int o = 0; o < kO; ++o) { d1 += P1[o] * shs[o]; d2 += P2[o] * shs[o]; }
      l1 += d1 * g;
      if (has2) l2 += d2 * g;
    } else {
      if (t < kO) out[(size_t)b * kO * kNC + t * kNC + c] = shs[t] * g;
    }
  }
}

}  // namespace

extern "C" void kernel_launch(void* const* d_in, const int* in_sizes, int n_in,
                              void* d_out, int out_size, void* d_ws, size_t ws_size,
                              hipStream_t stream) {
  const float* x = (const float*)d_in[0];   // [64, 8, 800] fp32
  const float* W = (const float*)d_in[1];   // [128, 800, 8, 16] fp32
  float* out = (float*)d_out;               // [64, 16, 128] fp32
  (void)in_sizes; (void)n_in; (void)out_size;

  if (ws_size >= WS_NEEDED) {
    unsigned short* Wb = (unsigned short*)d_ws;
    conv_w<<<dim3(kNC * 25), dim3(CT), 0, stream>>>(W, Wb);
    caps_route<<<dim3(kNC * kB), dim3(MT), 0, stream>>>(x, Wb, out);
  } else {
    caps_route_f32<<<dim3(kNC * kB), dim3(FT), 0, stream>>>(x, W, out);
  }
}

// Round 9
// 205.286 us; speedup vs baseline: 2.2045x; 2.2045x over previous
//
#include <hip/hip_runtime.h>
#include <math.h>

namespace {

constexpr int kB   = 64;
constexpr int kCin = 8;
constexpr int kR   = 800;
constexpr int kNC  = 128;
constexpr int kO   = 16;
constexpr int CT   = 256;   // conversion kernel TPB
constexpr int MT   = 512;   // main kernel TPB
constexpr int NITER = 3;
constexpr size_t WS_NEEDED =
    (size_t)kNC * kO * kR * kCin * sizeof(unsigned short);  // 26,214,400 B

typedef _Float16 half2v __attribute__((ext_vector_type(2)));

__device__ __forceinline__ half2v u2h(unsigned int u) {
  union { unsigned int u; half2v h; } x;
  x.u = u;
  return x.h;
}

__device__ __forceinline__ unsigned short f2h(float f) {
  union { _Float16 h; unsigned short s; } x;
  x.h = (_Float16)f;
  return x.s;
}

// DPP adds: xor1 = quad_perm{1,0,3,2}=0xB1, xor2 = quad_perm{2,3,0,1}=0x4E,
// mir8 = row_half_mirror (0x141): lane i <-> 7-i within each 8-lane half-row.
__device__ __forceinline__ float dpp_xor1_add(float v) {
  const int o = __builtin_amdgcn_mov_dpp(__float_as_int(v), 0xB1, 0xF, 0xF, true);
  return v + __int_as_float(o);
}
__device__ __forceinline__ float dpp_xor2_add(float v) {
  const int o = __builtin_amdgcn_mov_dpp(__float_as_int(v), 0x4E, 0xF, 0xF, true);
  return v + __int_as_float(o);
}
__device__ __forceinline__ float dpp_mir8_add(float v) {
  const int o = __builtin_amdgcn_mov_dpp(__float_as_int(v), 0x141, 0xF, 0xF, true);
  return v + __int_as_float(o);
}

// ---- W conversion: fp32 [c][r][i][o] -> fp16 [c][o][r][i] (uint4 = 8 i's) --
// R1-proven streaming 32-row tiles: 16.9 KB LDS -> 8 blocks/CU, 3200 blocks.
__global__ __launch_bounds__(CT) void conv_w(const float* __restrict__ W,
                                             unsigned short* __restrict__ Wb) {
  __shared__ float tile[32 * 132];   // 32 r-rows x 128 cols (+4 pad)
  const int blk = blockIdx.x;        // c*25 + rt
  const int c  = blk / 25;
  const int rt = blk - c * 25;
  const int r0 = rt * 32;
  const int t  = threadIdx.x;

  const float4* src =
      reinterpret_cast<const float4*>(W + ((size_t)c * kR + r0) * kCin * kO);
  #pragma unroll
  for (int k2 = 0; k2 < 4; ++k2) {
    const int i4  = t + k2 * CT;
    const float4 v = src[i4];
    const int fi = i4 * 4, row = fi >> 7, pos = fi & 127;
    *reinterpret_cast<float4*>(&tile[row * 132 + pos]) = v;
  }
  __syncthreads();

  const int o = t >> 4;
  #pragma unroll
  for (int k2 = 0; k2 < 2; ++k2) {
    const int rl = (t & 15) + 16 * k2;
    unsigned int pk[4];
    #pragma unroll
    for (int q = 0; q < 4; ++q) {
      const unsigned int lo = f2h(tile[rl * 132 + (2 * q + 0) * 16 + o]);
      const unsigned int hi = f2h(tile[rl * 132 + (2 * q + 1) * 16 + o]);
      pk[q] = lo | (hi << 16);
    }
    reinterpret_cast<uint4*>(Wb)[(size_t)(c * kO + o) * kR + (r0 + rl)] =
        make_uint4(pk[0], pk[1], pk[2], pk[3]);
  }
}

// ---- main (R9): R6 byte-for-byte EXCEPT the u1/u2 unpack arrays are
// deleted; sp- and d-loops read packed priors inline as (float)P[q].x/.y.
// clang folds these into v_fma_mix_f32 (fp16 source converted exactly inside
// the fp32 FMA) — numerically identical to R6, ~96 fewer v_cvt per thread,
// and strictly LOWER register pressure (no 32-fp32 u materialization).
// Clean single-variable test of whether phase-2 VALU is on the critical
// path. All proven pieces unchanged: single-b, 8192 blocks, (512,4),
// VGPR<=64 sweet spot, 8-deep load chunks, merged zero-conflict reduce. ----
__global__ __launch_bounds__(MT, 4) void caps_route(
    const float* __restrict__ x, const unsigned short* __restrict__ Wb,
    float* __restrict__ out) {
  constexpr int RST = 20;               // 17 cols + 3 pad (16B-aligned rows)
  __shared__ float red[128 * RST];      // 10 KB
  __shared__ float shs[RST];

  const int t = threadIdx.x;
  // XCD swizzle: 16 c's per XCD -> fp16 W working set 3.3 MB < 4 MB L2.
  const int j   = blockIdx.x;
  const int xcd = j & 7;
  const int kk  = j >> 3;               // 0..1023
  const int c   = ((kk >> 6) << 3) + xcd;
  const int b   = kk & 63;

  const float* xb  = x + (size_t)b * kCin * kR;
  const bool  has2 = (t < kR - MT);     // t < 288 owns second row r2
  const int   r1   = t, r2 = MT + t;

  // Priors stored packed o-pairs (R0-proven): 8 half2v per row.
  half2v P1[8], P2[8];
  #pragma unroll
  for (int q = 0; q < 8; ++q) P2[q] = half2v{(_Float16)0.f, (_Float16)0.f};

  const uint4* Wc = reinterpret_cast<const uint4*>(Wb) + (size_t)c * kO * kR;

  // -------- Phase 1: fdot2 rows; explicit 8-deep load chunks ----------------
  {
    half2v xp[4];
    #pragma unroll
    for (int q = 0; q < 4; ++q)
      xp[q] = half2v{(_Float16)xb[(2*q) * kR + r1], (_Float16)xb[(2*q+1) * kR + r1]};
    float p[16];
    #pragma unroll
    for (int ob = 0; ob < 2; ++ob) {
      uint4 w[8];
      #pragma unroll
      for (int u = 0; u < 8; ++u) w[u] = Wc[(size_t)(ob * 8 + u) * kR + r1];
      #pragma unroll
      for (int u = 0; u < 8; ++u) {
        float a = __builtin_amdgcn_fdot2(u2h(w[u].x), xp[0], 0.f, false);
        a = __builtin_amdgcn_fdot2(u2h(w[u].y), xp[1], a, false);
        a = __builtin_amdgcn_fdot2(u2h(w[u].z), xp[2], a, false);
        a = __builtin_amdgcn_fdot2(u2h(w[u].w), xp[3], a, false);
        p[ob * 8 + u] = a;
      }
    }
    #pragma unroll
    for (int q = 0; q < 8; ++q)
      P1[q] = half2v{(_Float16)p[2*q], (_Float16)p[2*q+1]};
  }
  if (has2) {
    half2v xp[4];
    #pragma unroll
    for (int q = 0; q < 4; ++q)
      xp[q] = half2v{(_Float16)xb[(2*q) * kR + r2], (_Float16)xb[(2*q+1) * kR + r2]};
    float p[16];
    #pragma unroll
    for (int ob = 0; ob < 2; ++ob) {
      uint4 w[8];
      #pragma unroll
      for (int u = 0; u < 8; ++u) w[u] = Wc[(size_t)(ob * 8 + u) * kR + r2];
      #pragma unroll
      for (int u = 0; u < 8; ++u) {
        float a = __builtin_amdgcn_fdot2(u2h(w[u].x), xp[0], 0.f, false);
        a = __builtin_amdgcn_fdot2(u2h(w[u].y), xp[1], a, false);
        a = __builtin_amdgcn_fdot2(u2h(w[u].z), xp[2], a, false);
        a = __builtin_amdgcn_fdot2(u2h(w[u].w), xp[3], a, false);
        p[ob * 8 + u] = a;
      }
    }
    #pragma unroll
    for (int q = 0; q < 8; ++q)
      P2[q] = half2v{(_Float16)p[2*q], (_Float16)p[2*q+1]};
  }

  // -------- Phase 2: 3 routing iterations (fp32 math, mix-FMA on packed P) --
  float l1 = 0.f, l2 = 0.f;
  #pragma unroll
  for (int it = 0; it < NITER; ++it) {
    const float e1 = (it == 0) ? 1.f : __expf(l1);
    const float e2 = has2 ? ((it == 0) ? 1.f : __expf(l2)) : 0.f;

    float sp[kO + 1];
    sp[kO] = e1 + e2;
    #pragma unroll
    for (int q = 0; q < 8; ++q) {
      sp[2*q]   = e1 * (float)P1[q].x + e2 * (float)P2[q].x;
      sp[2*q+1] = e1 * (float)P1[q].y + e2 * (float)P2[q].y;
    }

    #pragma unroll
    for (int v = 0; v <= kO; ++v) {
      sp[v] = dpp_xor1_add(sp[v]);
      sp[v] = dpp_xor2_add(sp[v]);
    }
    if ((t & 3) == 0) {
      float* row = &red[(t >> 2) * RST];
      #pragma unroll
      for (int q = 0; q < 4; ++q)
        *reinterpret_cast<float4*>(row + 4 * q) =
            make_float4(sp[4*q], sp[4*q+1], sp[4*q+2], sp[4*q+3]);
      row[16] = sp[16];
    }
    __syncthreads();

    // Merged stage 2+3 (R6-proven, zero bank conflicts):
    // t = col*8+q; 8-lane DPP group (fixed col) sums the 8 q-partials.
    if (t < 136) {
      const int q = t & 7, col = t >> 3;
      float a = 0.f;
      #pragma unroll
      for (int rr = 0; rr < 16; ++rr) a += red[(rr * 8 + q) * RST + col];
      a = dpp_xor1_add(a);
      a = dpp_xor2_add(a);
      a = dpp_mir8_add(a);
      if (q == 0) shs[col] = a;
    }
    __syncthreads();

    const float Zi = 1.f / shs[kO];
    float ss = 0.f;
    #pragma unroll
    for (int o = 0; o < kO; ++o) ss += shs[o] * shs[o];
    const float sn = ss * Zi * Zi;
    const float g  = Zi * sqrtf(sn) / (1.f + sn);

    if (it < NITER - 1) {
      float d1 = 0.f, d2 = 0.f;
      #pragma unroll
      for (int q = 0; q < 8; ++q) {
        d1 += (float)P1[q].x * shs[2*q] + (float)P1[q].y * shs[2*q+1];
        d2 += (float)P2[q].x * shs[2*q] + (float)P2[q].y * shs[2*q+1];
      }
      l1 += d1 * g;
      if (has2) l2 += d2 * g;
    } else {
      if (t < kO) out[(size_t)b * kO * kNC + t * kNC + c] = shs[t] * g;
    }
  }
}

// ---- fallback (no workspace): fp32 W direct — R6-proven kernel ------------
__global__ __launch_bounds__(MT, 4) void caps_route_f32(
    const float* __restrict__ x, const float* __restrict__ W,
    float* __restrict__ out) {
  constexpr int RST = 20;
  __shared__ float red[128 * RST];
  __shared__ float shs[RST];

  const int t   = threadIdx.x;
  const int j   = blockIdx.x;
  const int xcd = j & 7;
  const int kk  = j >> 3;
  const int c   = ((kk >> 6) << 3) + xcd;
  const int b   = kk & 63;

  const float* xb  = x + (size_t)b * kCin * kR;
  const bool  has2 = (t < kR - MT);
  const int   r1   = t, r2 = MT + t;

  float P1[kO], P2[kO];
  #pragma unroll
  for (int o = 0; o < kO; ++o) P2[o] = 0.f;
  {
    float xa[kCin];
    #pragma unroll
    for (int i = 0; i < kCin; ++i) xa[i] = xb[i * kR + r1];
    const float* Wc = W + ((size_t)c * kR + r1) * kCin * kO;
    #pragma unroll
    for (int o = 0; o < kO; ++o) {
      float acc = 0.f;
      #pragma unroll
      for (int i = 0; i < kCin; ++i) acc += xa[i] * Wc[i * kO + o];
      P1[o] = acc;
    }
  }
  if (has2) {
    float xa[kCin];
    #pragma unroll
    for (int i = 0; i < kCin; ++i) xa[i] = xb[i * kR + r2];
    const float* Wc = W + ((size_t)c * kR + r2) * kCin * kO;
    #pragma unroll
    for (int o = 0; o < kO; ++o) {
      float acc = 0.f;
      #pragma unroll
      for (int i = 0; i < kCin; ++i) acc += xa[i] * Wc[i * kO + o];
      P2[o] = acc;
    }
  }

  float l1 = 0.f, l2 = 0.f;
  #pragma unroll
  for (int it = 0; it < NITER; ++it) {
    const float e1 = (it == 0) ? 1.f : __expf(l1);
    const float e2 = has2 ? ((it == 0) ? 1.f : __expf(l2)) : 0.f;
    float sp[kO + 1];
    sp[kO] = e1 + e2;
    #pragma unroll
    for (int o = 0; o < kO; ++o) sp[o] = e1 * P1[o] + e2 * P2[o];
    #pragma unroll
    for (int v = 0; v <= kO; ++v) {
      sp[v] = dpp_xor1_add(sp[v]);
      sp[v] = dpp_xor2_add(sp[v]);
    }
    if ((t & 3) == 0) {
      float* row = &red[(t >> 2) * RST];
      #pragma unroll
      for (int q = 0; q < 4; ++q)
        *reinterpret_cast<float4*>(row + 4 * q) =
            make_float4(sp[4*q], sp[4*q+1], sp[4*q+2], sp[4*q+3]);
      row[16] = sp[16];
    }
    __syncthreads();
    if (t < 136) {
      const int q = t & 7, col = t >> 3;
      float a = 0.f;
      #pragma unroll
      for (int rr = 0; rr < 16; ++rr) a += red[(rr * 8 + q) * RST + col];
      a = dpp_xor1_add(a);
      a = dpp_xor2_add(a);
      a = dpp_mir8_add(a);
      if (q == 0) shs[col] = a;
    }
    __syncthreads();
    const float Zi = 1.f / shs[kO];
    float ss = 0.f;
    #pragma unroll
    for (int o = 0; o < kO; ++o) ss += shs[o] * shs[o];
    const float sn = ss * Zi * Zi;
    const float g  = Zi * sqrtf(sn) / (1.f + sn);
    if (it < NITER - 1) {
      float d1 = 0.f, d2 = 0.f;
      #pragma unroll
      for (int o = 0; o < kO; ++o) { d1 += P1[o] * shs[o]; d2 += P2[o] * shs[o]; }
      l1 += d1 * g;
      if (has2) l2 += d2 * g;
    } else {
      if (t < kO) out[(size_t)b * kO * kNC + t * kNC + c] = shs[t] * g;
    }
  }
}

}  // namespace

extern "C" void kernel_launch(void* const* d_in, const int* in_sizes, int n_in,
                              void* d_out, int out_size, void* d_ws, size_t ws_size,
                              hipStream_t stream) {
  const float* x = (const float*)d_in[0];   // [64, 8, 800] fp32
  const float* W = (const float*)d_in[1];   // [128, 800, 8, 16] fp32
  float* out = (float*)d_out;               // [64, 16, 128] fp32
  (void)in_sizes; (void)n_in; (void)out_size;

  if (ws_size >= WS_NEEDED) {
    unsigned short* Wb = (unsigned short*)d_ws;
    conv_w<<<dim3(kNC * 25), dim3(CT), 0, stream>>>(W, Wb);
    caps_route<<<dim3(kNC * kB), dim3(MT), 0, stream>>>(x, Wb, out);
  } else {
    caps_route_f32<<<dim3(kNC * kB), dim3(MT), 0, stream>>>(x, W, out);
  }
}

// Round 10
// 194.357 us; speedup vs baseline: 2.3285x; 1.0562x over previous
//
#include <hip/hip_runtime.h>
#include <math.h>

namespace {

constexpr int kB   = 64;
constexpr int kCin = 8;
constexpr int kR   = 800;
constexpr int kNC  = 128;
constexpr int kO   = 16;
constexpr int CT   = 256;   // conversion kernel TPB
constexpr int MT   = 512;   // main kernel TPB
constexpr int NITER = 3;
constexpr size_t WS_W = (size_t)kNC * kO * kR * kCin * sizeof(unsigned short); // 26,214,400
constexpr size_t WS_X = (size_t)kB * kCin * kR * sizeof(unsigned short);       // 819,200

typedef _Float16 half2v __attribute__((ext_vector_type(2)));

__device__ __forceinline__ half2v u2h(unsigned int u) {
  union { unsigned int u; half2v h; } x;
  x.u = u;
  return x.h;
}

__device__ __forceinline__ unsigned short f2h(float f) {
  union { _Float16 h; unsigned short s; } x;
  x.h = (_Float16)f;
  return x.s;
}

// DPP adds: xor1 = quad_perm{1,0,3,2}=0xB1, xor2 = quad_perm{2,3,0,1}=0x4E,
// mir8 = row_half_mirror (0x141): lane i <-> 7-i within each 8-lane half-row.
__device__ __forceinline__ float dpp_xor1_add(float v) {
  const int o = __builtin_amdgcn_mov_dpp(__float_as_int(v), 0xB1, 0xF, 0xF, true);
  return v + __int_as_float(o);
}
__device__ __forceinline__ float dpp_xor2_add(float v) {
  const int o = __builtin_amdgcn_mov_dpp(__float_as_int(v), 0x4E, 0xF, 0xF, true);
  return v + __int_as_float(o);
}
__device__ __forceinline__ float dpp_mir8_add(float v) {
  const int o = __builtin_amdgcn_mov_dpp(__float_as_int(v), 0x141, 0xF, 0xF, true);
  return v + __int_as_float(o);
}

// ---- conversion kernel: two roles by block index --------------------------
//  blk < 3200:  W fp32 [c][r][i][o] -> fp16 [c][o][r][i]  (R1-proven path)
//  blk >= 3200: x fp32 [b][i][r]    -> fp16 [b][r][i]     (R10: 64 blocks)
// Shared LDS pool sized for the larger (x) role: 25.7 KB -> 6 blocks/CU.
__global__ __launch_bounds__(CT) void conv_w(const float* __restrict__ W,
                                             unsigned short* __restrict__ Wb,
                                             const float* __restrict__ x,
                                             unsigned short* __restrict__ xh) {
  __shared__ float smem[kCin * 804];   // 25.7 KB; W path uses first 16.9 KB
  const int blk = blockIdx.x;
  const int t   = threadIdx.x;

  if (blk < kNC * 25) {
    // ---- W transpose (unchanged R1 path, tile viewed into smem) ----
    float* tile = smem;                // 32 r-rows x 132 (4224 floats)
    const int c  = blk / 25;
    const int rt = blk - c * 25;
    const int r0 = rt * 32;

    const float4* src =
        reinterpret_cast<const float4*>(W + ((size_t)c * kR + r0) * kCin * kO);
    #pragma unroll
    for (int k2 = 0; k2 < 4; ++k2) {
      const int i4  = t + k2 * CT;
      const float4 v = src[i4];
      const int fi = i4 * 4, row = fi >> 7, pos = fi & 127;
      *reinterpret_cast<float4*>(&tile[row * 132 + pos]) = v;
    }
    __syncthreads();

    const int o = t >> 4;
    #pragma unroll
    for (int k2 = 0; k2 < 2; ++k2) {
      const int rl = (t & 15) + 16 * k2;
      unsigned int pk[4];
      #pragma unroll
      for (int q = 0; q < 4; ++q) {
        const unsigned int lo = f2h(tile[rl * 132 + (2 * q + 0) * 16 + o]);
        const unsigned int hi = f2h(tile[rl * 132 + (2 * q + 1) * 16 + o]);
        pk[q] = lo | (hi << 16);
      }
      reinterpret_cast<uint4*>(Wb)[(size_t)(c * kO + o) * kR + (r0 + rl)] =
          make_uint4(pk[0], pk[1], pk[2], pk[3]);
    }
  } else {
    // ---- x transpose: one block per b ----
    const int b = blk - kNC * 25;      // 0..63
    const float4* src =
        reinterpret_cast<const float4*>(x + (size_t)b * kCin * kR);
    // load 8x800 fp32 into LDS rows of stride 804 (804%32=4 -> column reads
    // hit banks r+4i, conflict-free across i).
    #pragma unroll
    for (int k = 0; k < 7; ++k) {
      const int idx = t + k * CT;      // 0..1599 float4
      if (idx < kCin * kR / 4) {
        const float4 v = src[idx];
        const int i = idx / 200;       // 200 float4 per i-plane
        const int r = (idx - i * 200) * 4;
        float* dst = &smem[i * 804 + r];
        dst[0] = v.x; dst[1] = v.y; dst[2] = v.z; dst[3] = v.w;
      }
    }
    __syncthreads();
    // pack: xh[b][r] = uint4 of 8 halfs {(x0,x1),(x2,x3),(x4,x5),(x6,x7)}
    // -- same pair order caps_route's xp[q] expects.
    #pragma unroll
    for (int k = 0; k < 4; ++k) {
      const int r = t + k * CT;
      if (r < kR) {
        unsigned int pk[4];
        #pragma unroll
        for (int q = 0; q < 4; ++q) {
          const unsigned int lo = f2h(smem[(2 * q + 0) * 804 + r]);
          const unsigned int hi = f2h(smem[(2 * q + 1) * 804 + r]);
          pk[q] = lo | (hi << 16);
        }
        reinterpret_cast<uint4*>(xh)[(size_t)b * kR + r] =
            make_uint4(pk[0], pk[1], pk[2], pk[3]);
      }
    }
  }
}

// ---- main (R10): R9 byte-for-byte EXCEPT the x load path. If xh!=nullptr,
// each row's 4 xp pairs come from ONE uint4 load + bitcasts (vs 8 scalar
// loads + 8 cvt + 4 packs) — removes ~40 VALU + 14 memory ops from the HEAD
// of phase 1's dependency chain. xh==nullptr falls back to the R9 path
// (uniform sgpr branch). All proven pieces frozen: single-b, 8192 blocks,
// (512,4), VGPR<=64, 8-deep chunks, merged zero-conflict reduce, mix-FMA
// phase 2. ----
__global__ __launch_bounds__(MT, 4) void caps_route(
    const float* __restrict__ x, const unsigned short* __restrict__ Wb,
    const unsigned short* __restrict__ xh, float* __restrict__ out) {
  constexpr int RST = 20;               // 17 cols + 3 pad (16B-aligned rows)
  __shared__ float red[128 * RST];      // 10 KB
  __shared__ float shs[RST];

  const int t = threadIdx.x;
  // XCD swizzle: 16 c's per XCD -> fp16 W working set 3.3 MB < 4 MB L2.
  const int j   = blockIdx.x;
  const int xcd = j & 7;
  const int kk  = j >> 3;               // 0..1023
  const int c   = ((kk >> 6) << 3) + xcd;
  const int b   = kk & 63;

  const float* xb  = x + (size_t)b * kCin * kR;
  const bool  has2 = (t < kR - MT);     // t < 288 owns second row r2
  const int   r1   = t, r2 = MT + t;

  // Priors stored packed o-pairs (R0-proven): 8 half2v per row.
  half2v P1[8], P2[8];
  #pragma unroll
  for (int q = 0; q < 8; ++q) P2[q] = half2v{(_Float16)0.f, (_Float16)0.f};

  const uint4* Wc = reinterpret_cast<const uint4*>(Wb) + (size_t)c * kO * kR;
  const uint4* xv = xh ? reinterpret_cast<const uint4*>(xh) + (size_t)b * kR
                       : nullptr;

  // -------- Phase 1: fdot2 rows; explicit 8-deep load chunks ----------------
  {
    half2v xp[4];
    if (xv) {
      const uint4 xr = xv[r1];
      xp[0] = u2h(xr.x); xp[1] = u2h(xr.y); xp[2] = u2h(xr.z); xp[3] = u2h(xr.w);
    } else {
      #pragma unroll
      for (int q = 0; q < 4; ++q)
        xp[q] = half2v{(_Float16)xb[(2*q) * kR + r1], (_Float16)xb[(2*q+1) * kR + r1]};
    }
    float p[16];
    #pragma unroll
    for (int ob = 0; ob < 2; ++ob) {
      uint4 w[8];
      #pragma unroll
      for (int u = 0; u < 8; ++u) w[u] = Wc[(size_t)(ob * 8 + u) * kR + r1];
      #pragma unroll
      for (int u = 0; u < 8; ++u) {
        float a = __builtin_amdgcn_fdot2(u2h(w[u].x), xp[0], 0.f, false);
        a = __builtin_amdgcn_fdot2(u2h(w[u].y), xp[1], a, false);
        a = __builtin_amdgcn_fdot2(u2h(w[u].z), xp[2], a, false);
        a = __builtin_amdgcn_fdot2(u2h(w[u].w), xp[3], a, false);
        p[ob * 8 + u] = a;
      }
    }
    #pragma unroll
    for (int q = 0; q < 8; ++q)
      P1[q] = half2v{(_Float16)p[2*q], (_Float16)p[2*q+1]};
  }
  if (has2) {
    half2v xp[4];
    if (xv) {
      const uint4 xr = xv[r2];
      xp[0] = u2h(xr.x); xp[1] = u2h(xr.y); xp[2] = u2h(xr.z); xp[3] = u2h(xr.w);
    } else {
      #pragma unroll
      for (int q = 0; q < 4; ++q)
        xp[q] = half2v{(_Float16)xb[(2*q) * kR + r2], (_Float16)xb[(2*q+1) * kR + r2]};
    }
    float p[16];
    #pragma unroll
    for (int ob = 0; ob < 2; ++ob) {
      uint4 w[8];
      #pragma unroll
      for (int u = 0; u < 8; ++u) w[u] = Wc[(size_t)(ob * 8 + u) * kR + r2];
      #pragma unroll
      for (int u = 0; u < 8; ++u) {
        float a = __builtin_amdgcn_fdot2(u2h(w[u].x), xp[0], 0.f, false);
        a = __builtin_amdgcn_fdot2(u2h(w[u].y), xp[1], a, false);
        a = __builtin_amdgcn_fdot2(u2h(w[u].z), xp[2], a, false);
        a = __builtin_amdgcn_fdot2(u2h(w[u].w), xp[3], a, false);
        p[ob * 8 + u] = a;
      }
    }
    #pragma unroll
    for (int q = 0; q < 8; ++q)
      P2[q] = half2v{(_Float16)p[2*q], (_Float16)p[2*q+1]};
  }

  // -------- Phase 2: 3 routing iterations (fp32 math, mix-FMA on packed P) --
  float l1 = 0.f, l2 = 0.f;
  #pragma unroll
  for (int it = 0; it < NITER; ++it) {
    const float e1 = (it == 0) ? 1.f : __expf(l1);
    const float e2 = has2 ? ((it == 0) ? 1.f : __expf(l2)) : 0.f;

    float sp[kO + 1];
    sp[kO] = e1 + e2;
    #pragma unroll
    for (int q = 0; q < 8; ++q) {
      sp[2*q]   = e1 * (float)P1[q].x + e2 * (float)P2[q].x;
      sp[2*q+1] = e1 * (float)P1[q].y + e2 * (float)P2[q].y;
    }

    #pragma unroll
    for (int v = 0; v <= kO; ++v) {
      sp[v] = dpp_xor1_add(sp[v]);
      sp[v] = dpp_xor2_add(sp[v]);
    }
    if ((t & 3) == 0) {
      float* row = &red[(t >> 2) * RST];
      #pragma unroll
      for (int q = 0; q < 4; ++q)
        *reinterpret_cast<float4*>(row + 4 * q) =
            make_float4(sp[4*q], sp[4*q+1], sp[4*q+2], sp[4*q+3]);
      row[16] = sp[16];
    }
    __syncthreads();

    // Merged stage 2+3 (R6-proven, zero bank conflicts):
    // t = col*8+q; 8-lane DPP group (fixed col) sums the 8 q-partials.
    if (t < 136) {
      const int q = t & 7, col = t >> 3;
      float a = 0.f;
      #pragma unroll
      for (int rr = 0; rr < 16; ++rr) a += red[(rr * 8 + q) * RST + col];
      a = dpp_xor1_add(a);
      a = dpp_xor2_add(a);
      a = dpp_mir8_add(a);
      if (q == 0) shs[col] = a;
    }
    __syncthreads();

    const float Zi = 1.f / shs[kO];
    float ss = 0.f;
    #pragma unroll
    for (int o = 0; o < kO; ++o) ss += shs[o] * shs[o];
    const float sn = ss * Zi * Zi;
    const float g  = Zi * sqrtf(sn) / (1.f + sn);

    if (it < NITER - 1) {
      float d1 = 0.f, d2 = 0.f;
      #pragma unroll
      for (int q = 0; q < 8; ++q) {
        d1 += (float)P1[q].x * shs[2*q] + (float)P1[q].y * shs[2*q+1];
        d2 += (float)P2[q].x * shs[2*q] + (float)P2[q].y * shs[2*q+1];
      }
      l1 += d1 * g;
      if (has2) l2 += d2 * g;
    } else {
      if (t < kO) out[(size_t)b * kO * kNC + t * kNC + c] = shs[t] * g;
    }
  }
}

// ---- fallback (no workspace): fp32 W direct — R6-proven kernel ------------
__global__ __launch_bounds__(MT, 4) void caps_route_f32(
    const float* __restrict__ x, const float* __restrict__ W,
    float* __restrict__ out) {
  constexpr int RST = 20;
  __shared__ float red[128 * RST];
  __shared__ float shs[RST];

  const int t   = threadIdx.x;
  const int j   = blockIdx.x;
  const int xcd = j & 7;
  const int kk  = j >> 3;
  const int c   = ((kk >> 6) << 3) + xcd;
  const int b   = kk & 63;

  const float* xb  = x + (size_t)b * kCin * kR;
  const bool  has2 = (t < kR - MT);
  const int   r1   = t, r2 = MT + t;

  float P1[kO], P2[kO];
  #pragma unroll
  for (int o = 0; o < kO; ++o) P2[o] = 0.f;
  {
    float xa[kCin];
    #pragma unroll
    for (int i = 0; i < kCin; ++i) xa[i] = xb[i * kR + r1];
    const float* Wc = W + ((size_t)c * kR + r1) * kCin * kO;
    #pragma unroll
    for (int o = 0; o < kO; ++o) {
      float acc = 0.f;
      #pragma unroll
      for (int i = 0; i < kCin; ++i) acc += xa[i] * Wc[i * kO + o];
      P1[o] = acc;
    }
  }
  if (has2) {
    float xa[kCin];
    #pragma unroll
    for (int i = 0; i < kCin; ++i) xa[i] = xb[i * kR + r2];
    const float* Wc = W + ((size_t)c * kR + r2) * kCin * kO;
    #pragma unroll
    for (int o = 0; o < kO; ++o) {
      float acc = 0.f;
      #pragma unroll
      for (int i = 0; i < kCin; ++i) acc += xa[i] * Wc[i * kO + o];
      P2[o] = acc;
    }
  }

  float l1 = 0.f, l2 = 0.f;
  #pragma unroll
  for (int it = 0; it < NITER; ++it) {
    const float e1 = (it == 0) ? 1.f : __expf(l1);
    const float e2 = has2 ? ((it == 0) ? 1.f : __expf(l2)) : 0.f;
    float sp[kO + 1];
    sp[kO] = e1 + e2;
    #pragma unroll
    for (int o = 0; o < kO; ++o) sp[o] = e1 * P1[o] + e2 * P2[o];
    #pragma unroll
    for (int v = 0; v <= kO; ++v) {
      sp[v] = dpp_xor1_add(sp[v]);
      sp[v] = dpp_xor2_add(sp[v]);
    }
    if ((t & 3) == 0) {
      float* row = &red[(t >> 2) * RST];
      #pragma unroll
      for (int q = 0; q < 4; ++q)
        *reinterpret_cast<float4*>(row + 4 * q) =
            make_float4(sp[4*q], sp[4*q+1], sp[4*q+2], sp[4*q+3]);
      row[16] = sp[16];
    }
    __syncthreads();
    if (t < 136) {
      const int q = t & 7, col = t >> 3;
      float a = 0.f;
      #pragma unroll
      for (int rr = 0; rr < 16; ++rr) a += red[(rr * 8 + q) * RST + col];
      a = dpp_xor1_add(a);
      a = dpp_xor2_add(a);
      a = dpp_mir8_add(a);
      if (q == 0) shs[col] = a;
    }
    __syncthreads();
    const float Zi = 1.f / shs[kO];
    float ss = 0.f;
    #pragma unroll
    for (int o = 0; o < kO; ++o) ss += shs[o] * shs[o];
    const float sn = ss * Zi * Zi;
    const float g  = Zi * sqrtf(sn) / (1.f + sn);
    if (it < NITER - 1) {
      float d1 = 0.f, d2 = 0.f;
      #pragma unroll
      for (int o = 0; o < kO; ++o) { d1 += P1[o] * shs[o]; d2 += P2[o] * shs[o]; }
      l1 += d1 * g;
      if (has2) l2 += d2 * g;
    } else {
      if (t < kO) out[(size_t)b * kO * kNC + t * kNC + c] = shs[t] * g;
    }
  }
}

}  // namespace

extern "C" void kernel_launch(void* const* d_in, const int* in_sizes, int n_in,
                              void* d_out, int out_size, void* d_ws, size_t ws_size,
                              hipStream_t stream) {
  const float* x = (const float*)d_in[0];   // [64, 8, 800] fp32
  const float* W = (const float*)d_in[1];   // [128, 800, 8, 16] fp32
  float* out = (float*)d_out;               // [64, 16, 128] fp32
  (void)in_sizes; (void)n_in; (void)out_size;

  if (ws_size >= WS_W + WS_X) {
    unsigned short* Wb = (unsigned short*)d_ws;
    unsigned short* xh = (unsigned short*)((char*)d_ws + WS_W);
    conv_w<<<dim3(kNC * 25 + kB), dim3(CT), 0, stream>>>(W, Wb, x, xh);
    caps_route<<<dim3(kNC * kB), dim3(MT), 0, stream>>>(x, Wb, xh, out);
  } else if (ws_size >= WS_W) {
    unsigned short* Wb = (unsigned short*)d_ws;
    conv_w<<<dim3(kNC * 25), dim3(CT), 0, stream>>>(W, Wb, x, nullptr);
    caps_route<<<dim3(kNC * kB), dim3(MT), 0, stream>>>(x, Wb, nullptr, out);
  } else {
    caps_route_f32<<<dim3(kNC * kB), dim3(MT), 0, stream>>>(x, W, out);
  }
}